// Round 11
// baseline (192.420 us; speedup 1.0000x reference)
//
#include <hip/hip_runtime.h>
#include <math.h>

// N=100000 nodes, E=6400000 edges, avg degree 64.
// out[n] = [cos(th_n), sin(th_n), w_n],  w_n = S_y / max(||S||, eps),
//   S_x = cos(th)*C + sin(th)*S,  S_y = cos(th)*S - sin(th)*C,
//   C_n = sum_{e:dst=n} cos(x[src_e]),  S_n = sum_{e:dst=n} sin(x[src_e]).
//
// Model (R1-R10): global fp atomics write through to HBM (634us, R1/R8).
// fp32 LDS lane-atomic ~1.65cyc/CU; u64 ds_add ~2 slots (~20us for E).
// R10 (one u64 LDS atomic/edge, inline sincos) = 112us scatter but
// VALUBusy 52%: sincos+pack issued 16x per edge (once per partition block,
// ~98% wave-hit-rate => no execz skip). R11: precompute the PACKED u64
// addend per node (pu[n], 800KB, L2-resident) in a prep kernel; the 16x
// scan body is now int4 loads + cmp + masked 8B gather + ds_add_u64 only.
// Per-visit VALU ~5 insts; sincos count N instead of 16E.
// Fixed-point: addend=(1<<52)|(sin+32768)<<26|(cos+32768), scale 2^15;
// deg_max ~120 << 1024 => no cross-field carry; decode in reduce.

#define EPS 1e-12f
#define NPART 16
#define RMAX 6250      // u64[6250] = 50KB LDS -> 3 blocks/CU
#define BLK 512

static __device__ __forceinline__ unsigned long long pack_cs(float xv) {
    float sn, cs;
    __sincosf(xv, &sn, &cs);
    const int ci = __float2int_rn(cs * 32768.0f);   // [-32768, 32768]
    const int si = __float2int_rn(sn * 32768.0f);
    return (1ull << 52)
         | ((unsigned long long)(unsigned)(si + 32768) << 26)
         | (unsigned long long)(unsigned)(ci + 32768);
}

// ---------------- prep: packed-addend table ----------------
__global__ __launch_bounds__(256) void prep_pack_kernel(
        const float* __restrict__ x,
        unsigned long long* __restrict__ pu, int N) {
    int i = blockIdx.x * blockDim.x + threadIdx.x;
    if (i < N) pu[i] = pack_cs(x[i]);
}

// ---------------- scatter: cheap scan body + one u64 LDS atomic/edge ----
__global__ __launch_bounds__(BLK) void scatter_kernel(
        const unsigned long long* __restrict__ pu,
        const int* __restrict__ esrc,
        const int* __restrict__ edst,
        unsigned long long* __restrict__ partials,   // [NPART*nslice][R]
        int E, int R, int nslice) {
    __shared__ unsigned long long lacc[RMAX];
    const int p = blockIdx.x / nslice;
    const int s = blockIdx.x % nslice;   // nslice%8==0 -> XCD = blk%8 = s%8
    const int pBeg = p * R;

    for (int k = threadIdx.x; k < R; k += BLK) lacc[k] = 0ull;
    __syncthreads();

    const int per = (((E + nslice - 1) / nslice) + 3) & ~3;
    const int beg = s * per;
    const int end = min(beg + per, E);
    const int end4 = beg + (max(end - beg, 0) & ~3);

    for (int i = beg + threadIdx.x * 4; i < end4; i += BLK * 4) {
        const int4 d4 = *(const int4*)&edst[i];
        const int4 s4 = *(const int4*)&esrc[i];
        const unsigned dl0 = (unsigned)(d4.x - pBeg);
        const unsigned dl1 = (unsigned)(d4.y - pBeg);
        const unsigned dl2 = (unsigned)(d4.z - pBeg);
        const unsigned dl3 = (unsigned)(d4.w - pBeg);
        const bool h0 = dl0 < (unsigned)R;
        const bool h1 = dl1 < (unsigned)R;
        const bool h2 = dl2 < (unsigned)R;
        const bool h3 = dl3 < (unsigned)R;
        // masked 8B gathers from the L2-resident packed table; issued
        // before any atomic so the loads pipeline behind one drain
        unsigned long long v0 = 0ull, v1 = 0ull, v2 = 0ull, v3 = 0ull;
        if (h0) v0 = pu[s4.x];
        if (h1) v1 = pu[s4.y];
        if (h2) v2 = pu[s4.z];
        if (h3) v3 = pu[s4.w];
        if (h0) atomicAdd(&lacc[dl0], v0);
        if (h1) atomicAdd(&lacc[dl1], v1);
        if (h2) atomicAdd(&lacc[dl2], v2);
        if (h3) atomicAdd(&lacc[dl3], v3);
    }
    for (int i = end4 + threadIdx.x; i < end; i += BLK) {
        const unsigned dl = (unsigned)(edst[i] - pBeg);
        if (dl < (unsigned)R) atomicAdd(&lacc[dl], pu[esrc[i]]);
    }

    __syncthreads();
    unsigned long long* dst = partials + (size_t)blockIdx.x * R;
    for (int k = threadIdx.x; k < R; k += BLK) dst[k] = lacc[k];
}

// ---------------- reduce partials (raw u64 sum) + epilogue ----------------
__global__ __launch_bounds__(256) void reduce_kernel(
        const float* __restrict__ theta,
        const unsigned long long* __restrict__ partials,
        float* __restrict__ out, int N, int R, int nslice) {
    const int n = blockIdx.x * blockDim.x + threadIdx.x;
    if (n >= N) return;
    const int p = n / R;
    const int j = n - p * R;
    const unsigned long long* base = partials + (size_t)p * nslice * R + j;
    unsigned long long t = 0ull;
    #pragma unroll 8
    for (int s = 0; s < nslice; ++s) t += base[(size_t)s * R];
    const long long k  = (long long)(t >> 52);
    const long long cf = (long long)(t & 0x3FFFFFFull);
    const long long sf = (long long)((t >> 26) & 0x3FFFFFFull);
    const float C  = (float)(cf - k * 32768) * (1.0f / 32768.0f);
    const float Sv = (float)(sf - k * 32768) * (1.0f / 32768.0f);
    float sn, cs;
    __sincosf(theta[n], &sn, &cs);
    const float nrm = fmaxf(sqrtf(C * C + Sv * Sv), EPS);
    out[3 * n + 0] = cs;
    out[3 * n + 1] = sn;
    out[3 * n + 2] = (cs * Sv - sn * C) / nrm;
}

// ---------------- fallback: global native atomics (R8, correct @719us) ----
__global__ __launch_bounds__(256) void prep_acc_kernel(float2* __restrict__ acc, int N) {
    int i = blockIdx.x * blockDim.x + threadIdx.x;
    if (i < N) acc[i] = make_float2(0.0f, 0.0f);
}

__global__ __launch_bounds__(256) void edge_scatter_sincos_kernel(
        const int* __restrict__ esrc,
        const int* __restrict__ edst,
        const float* __restrict__ x,
        float2* __restrict__ acc, int E) {
    const int i = (blockIdx.x * 256 + threadIdx.x) * 4;
    float* accf = (float*)acc;
    for (int k = i; k < min(i + 4, E); ++k) {
        float sn, cs;
        __sincosf(x[esrc[k]], &sn, &cs);
        const int d = edst[k];
        unsafeAtomicAdd(&accf[2 * d],     cs);
        unsafeAtomicAdd(&accf[2 * d + 1], sn);
    }
}

__global__ __launch_bounds__(256) void node_kernel(
        const float* __restrict__ theta,
        const float2* __restrict__ acc,
        float* __restrict__ out, int N) {
    int n = blockIdx.x * blockDim.x + threadIdx.x;
    if (n >= N) return;
    float sn, cs;
    __sincosf(theta[n], &sn, &cs);
    const float2 a = acc[n];
    const float nrm = fmaxf(sqrtf(a.x * a.x + a.y * a.y), EPS);
    out[3 * n + 0] = cs;
    out[3 * n + 1] = sn;
    out[3 * n + 2] = (cs * a.y - sn * a.x) / nrm;
}

extern "C" void kernel_launch(void* const* d_in, const int* in_sizes, int n_in,
                              void* d_out, int out_size, void* d_ws, size_t ws_size,
                              hipStream_t stream) {
    const float* x     = (const float*)d_in[0];
    const float* theta = (const float*)d_in[1];
    const int*   esrc  = (const int*)d_in[2];
    const int*   edst  = (const int*)d_in[3];
    float*       out   = (float*)d_out;

    const int N = in_sizes[0];
    const int E = in_sizes[2];
    const int R = (N + NPART - 1) / NPART;

    const size_t pu_bytes = (size_t)N * sizeof(unsigned long long);

    if (R <= RMAX) {
        // largest nslice (multiple of 8) whose buffers fit in ws
        for (int nslice : {48, 24, 8}) {
            const size_t part_bytes = (size_t)NPART * nslice * R * sizeof(unsigned long long);
            if (ws_size >= part_bytes + pu_bytes) {
                unsigned long long* partials = (unsigned long long*)d_ws;
                unsigned long long* pu = (unsigned long long*)((char*)d_ws + part_bytes);
                prep_pack_kernel<<<(N + 255) / 256, 256, 0, stream>>>(x, pu, N);
                scatter_kernel<<<NPART * nslice, BLK, 0, stream>>>(
                    pu, esrc, edst, partials, E, R, nslice);
                reduce_kernel<<<(N + 255) / 256, 256, 0, stream>>>(
                    theta, partials, out, N, R, nslice);
                return;
            }
        }
    }

    // fallback: global native atomics (passed correctness in R8)
    float2* acc = (float2*)d_ws;   // 800KB
    prep_acc_kernel<<<(N + 255) / 256, 256, 0, stream>>>(acc, N);
    edge_scatter_sincos_kernel<<<(E + 1023) / 1024, 256, 0, stream>>>(esrc, edst, x, acc, E);
    node_kernel<<<(N + 255) / 256, 256, 0, stream>>>(theta, acc, out, N);
}